// Round 1
// baseline (2629.202 us; speedup 1.0000x reference)
//
#include <hip/hip_runtime.h>
#include <math.h>

// Problem constants
// L=32768 lines, M=8 neighbors, B=8192 blocks, LIN=BIN=768, H=512, NH=8, DH=64

__device__ __forceinline__ float gelu_exact(float x) {
    return 0.5f * x * (1.0f + erff(x * 0.70710678118654752440f));
}

// Block-wide reduction of two values across 256 threads (4 waves).
__device__ __forceinline__ void breduce2(float& s0, float& s1, float* sm) {
    #pragma unroll
    for (int off = 32; off > 0; off >>= 1) {
        s0 += __shfl_down(s0, off);
        s1 += __shfl_down(s1, off);
    }
    const int lane = threadIdx.x & 63, w = threadIdx.x >> 6;
    __syncthreads();             // safe for repeated calls on same sm
    if (lane == 0) { sm[w * 2] = s0; sm[w * 2 + 1] = s1; }
    __syncthreads();
    s0 = sm[0] + sm[2] + sm[4] + sm[6];
    s1 = sm[1] + sm[3] + sm[5] + sm[7];
}

// ---------------- GEMM: C[M,N] = A[M,K] @ W[N,K]^T (+bias) ----------------
// A may be split at column K1 between two buffers (concat along K).
// Block tile 64x64, BK=16, 256 threads, 4x4 accumulators per thread.
template<bool HAS_A2, bool HAS_BIAS>
__global__ __launch_bounds__(256) void gemm_tn(
    const float* __restrict__ A1, const float* __restrict__ A2, int K1, int K,
    const float* __restrict__ W, const float* __restrict__ bias,
    float* __restrict__ C, int N)
{
    __shared__ float As[16][65];
    __shared__ float Ws[16][65];
    const int tx = threadIdx.x & 15;
    const int ty = threadIdx.x >> 4;
    const int row0 = blockIdx.y * 64;
    const int col0 = blockIdx.x * 64;
    const int lr = threadIdx.x >> 2;         // 0..63: tile row to stage
    const int lc = (threadIdx.x & 3) << 2;   // 0,4,8,12: tile col (float4)
    float acc[4][4] = {};

    for (int k0 = 0; k0 < K; k0 += 16) {
        const float* Asrc = (!HAS_A2 || k0 < K1) ? A1 : A2;
        const int ld = (!HAS_A2) ? K : ((k0 < K1) ? K1 : (K - K1));
        const int kb = (!HAS_A2 || k0 < K1) ? k0 : (k0 - K1);
        const float4 av = *reinterpret_cast<const float4*>(
            &Asrc[(size_t)(row0 + lr) * ld + kb + lc]);
        const float4 wv = *reinterpret_cast<const float4*>(
            &W[(size_t)(col0 + lr) * K + k0 + lc]);
        As[lc + 0][lr] = av.x; As[lc + 1][lr] = av.y;
        As[lc + 2][lr] = av.z; As[lc + 3][lr] = av.w;
        Ws[lc + 0][lr] = wv.x; Ws[lc + 1][lr] = wv.y;
        Ws[lc + 2][lr] = wv.z; Ws[lc + 3][lr] = wv.w;
        __syncthreads();
        #pragma unroll
        for (int kk = 0; kk < 16; ++kk) {
            float a[4], b[4];
            #pragma unroll
            for (int i = 0; i < 4; ++i) a[i] = As[kk][ty * 4 + i];
            #pragma unroll
            for (int j = 0; j < 4; ++j) b[j] = Ws[kk][tx * 4 + j];
            #pragma unroll
            for (int i = 0; i < 4; ++i)
                #pragma unroll
                for (int j = 0; j < 4; ++j)
                    acc[i][j] = fmaf(a[i], b[j], acc[i][j]);
        }
        __syncthreads();
    }
    #pragma unroll
    for (int i = 0; i < 4; ++i) {
        const int r = row0 + ty * 4 + i;
        #pragma unroll
        for (int j = 0; j < 4; ++j) {
            const int c = col0 + tx * 4 + j;
            float v = acc[i][j];
            if (HAS_BIAS) v += bias[c];
            C[(size_t)r * N + c] = v;
        }
    }
}

// ---------------- Row LayerNorm (in-place), 512 cols, optional GELU ----------------
template<bool GELU>
__global__ __launch_bounds__(256) void ln_rows(
    float* __restrict__ X, const float* __restrict__ g, const float* __restrict__ b)
{
    __shared__ float sm[8];
    const size_t base = (size_t)blockIdx.x * 512;
    const int t = threadIdx.x;
    float x0 = X[base + t], x1 = X[base + t + 256];
    float s0 = x0 + x1, s1 = x0 * x0 + x1 * x1;
    breduce2(s0, s1, sm);
    const float mu = s0 * (1.0f / 512.0f);
    const float var = s1 * (1.0f / 512.0f) - mu * mu;
    const float rs = rsqrtf(var + 1e-5f);
    float y0 = (x0 - mu) * rs * g[t] + b[t];
    float y1 = (x1 - mu) * rs * g[t + 256] + b[t + 256];
    if (GELU) { y0 = gelu_exact(y0); y1 = gelu_exact(y1); }
    X[base + t] = y0; X[base + t + 256] = y1;
}

// ---------------- Attention: one block per line, one wave per head ----------------
__global__ __launch_bounds__(512) void attn_kernel(
    const float* __restrict__ qh, const float* __restrict__ kvb,
    const int* __restrict__ kidx, const int* __restrict__ ncnt,
    float* __restrict__ ctx)
{
    const int l = blockIdx.x;
    const int head = threadIdx.x >> 6;
    const int lane = threadIdx.x & 63;
    const int cnt = ncnt[l];
    const float qv = qh[(size_t)l * 512 + head * 64 + lane];
    int idx[8];
    #pragma unroll
    for (int m = 0; m < 8; ++m) idx[m] = kidx[l * 8 + m];
    float sc[8];
    #pragma unroll
    for (int m = 0; m < 8; ++m) {
        float p = qv * kvb[(size_t)idx[m] * 1024 + head * 64 + lane];
        #pragma unroll
        for (int off = 32; off > 0; off >>= 1) p += __shfl_xor(p, off);
        sc[m] = (m < cnt) ? p * 0.125f : -3.402823466e38f;
    }
    float mx = sc[0];
    #pragma unroll
    for (int m = 1; m < 8; ++m) mx = fmaxf(mx, sc[m]);
    float w[8], s = 0.0f;
    #pragma unroll
    for (int m = 0; m < 8; ++m) { w[m] = expf(sc[m] - mx); s += w[m]; }
    float o = 0.0f;
    #pragma unroll
    for (int m = 0; m < 8; ++m)
        o += w[m] * kvb[(size_t)idx[m] * 1024 + 512 + head * 64 + lane];
    ctx[(size_t)l * 512 + head * 64 + lane] = o / s;
}

// ---------------- Final: h2 = h1 + gelu(LN(h2_raw)); out = sigmoid(h2.head_w + head_b) ----------------
__global__ __launch_bounds__(256) void final_head(
    const float* __restrict__ h1, const float* __restrict__ h2raw,
    const float* __restrict__ g, const float* __restrict__ b,
    const float* __restrict__ hw, const float* __restrict__ hb,
    float* __restrict__ out)
{
    __shared__ float sm[8];
    const size_t base = (size_t)blockIdx.x * 512;
    const int t = threadIdx.x;
    const float x0 = h2raw[base + t], x1 = h2raw[base + t + 256];
    float s0 = x0 + x1, s1 = x0 * x0 + x1 * x1;
    breduce2(s0, s1, sm);
    const float mu = s0 * (1.0f / 512.0f);
    const float var = s1 * (1.0f / 512.0f) - mu * mu;
    const float rs = rsqrtf(var + 1e-5f);
    const float y0 = h1[base + t]       + gelu_exact((x0 - mu) * rs * g[t]       + b[t]);
    const float y1 = h1[base + t + 256] + gelu_exact((x1 - mu) * rs * g[t + 256] + b[t + 256]);
    float d0 = y0 * hw[t] + y1 * hw[t + 256], d1 = 0.0f;
    breduce2(d0, d1, sm);
    if (t == 0) out[blockIdx.x] = 1.0f / (1.0f + expf(-(d0 + hb[0])));
}

extern "C" void kernel_launch(void* const* d_in, const int* in_sizes, int n_in,
                              void* d_out, int out_size, void* d_ws, size_t ws_size,
                              hipStream_t stream)
{
    const float* lines  = (const float*)d_in[0];   // [32768,768]
    const float* blocks = (const float*)d_in[1];   // [8192,768]
    const float* Wq     = (const float*)d_in[2];   // [512,768]
    const float* Wkv    = (const float*)d_in[3];   // [512,768]
    const float* qn_g   = (const float*)d_in[4];
    const float* qn_b   = (const float*)d_in[5];
    const float* kvn_g  = (const float*)d_in[6];
    const float* kvn_b  = (const float*)d_in[7];
    const float* in_w   = (const float*)d_in[8];   // [1536,512]
    const float* in_b   = (const float*)d_in[9];   // [1536]
    const float* out_w  = (const float*)d_in[10];  // [512,512]
    const float* out_b  = (const float*)d_in[11];
    const float* p1_w   = (const float*)d_in[12];  // [512,1024]
    const float* p1_b   = (const float*)d_in[13];
    const float* ln1_g  = (const float*)d_in[14];
    const float* ln1_b  = (const float*)d_in[15];
    const float* p2_w   = (const float*)d_in[16];  // [512,512]
    const float* p2_b   = (const float*)d_in[17];
    const float* ln2_g  = (const float*)d_in[18];
    const float* ln2_b  = (const float*)d_in[19];
    const float* head_w = (const float*)d_in[20];  // [1,512]
    const float* head_b = (const float*)d_in[21];  // [1]
    const int*   kidx   = (const int*)d_in[22];    // [32768,8]
    const int*   ncnt   = (const int*)d_in[23];    // [32768]
    float* out = (float*)d_out;                    // [32768]

    float* ws  = (float*)d_ws;
    float* q   = ws;                          // [32768*512] q (later h2_raw)
    float* qh  = ws + 16777216;               // [32768*512] qh -> attn_out
    float* cx  = ws + 2 * 16777216;           // [32768*512] ctx -> h1
    float* bkv = ws + 3 * 16777216;           // [8192*512]
    float* kvb = ws + 3 * 16777216 + 4194304; // [8192*1024] (k | v)

    const dim3 blk(256);

    // 1. bkv_raw = block_reprs @ Wkv^T          [8192,512]
    gemm_tn<false, false><<<dim3(8, 128), blk, 0, stream>>>(
        blocks, nullptr, 768, 768, Wkv, nullptr, bkv, 512);
    // 2. bkv = LN(bkv_raw)
    ln_rows<false><<<8192, blk, 0, stream>>>(bkv, kvn_g, kvn_b);
    // 3. kvb = bkv @ [wk;wv]^T + [bk;bv]        [8192,1024]
    gemm_tn<false, true><<<dim3(16, 128), blk, 0, stream>>>(
        bkv, nullptr, 512, 512, in_w + 512 * 512, in_b + 512, kvb, 1024);
    // 4. q_raw = lines @ Wq^T                   [32768,512]
    gemm_tn<false, false><<<dim3(8, 512), blk, 0, stream>>>(
        lines, nullptr, 768, 768, Wq, nullptr, q, 512);
    // 5. q = LN(q_raw)
    ln_rows<false><<<32768, blk, 0, stream>>>(q, qn_g, qn_b);
    // 6. qh = q @ wq_i^T + bq_i                 [32768,512]
    gemm_tn<false, true><<<dim3(8, 512), blk, 0, stream>>>(
        q, nullptr, 512, 512, in_w, in_b, qh, 512);
    // 7. ctx (attention)                        [32768,512]
    attn_kernel<<<32768, dim3(512), 0, stream>>>(qh, kvb, kidx, ncnt, cx);
    // 8. attn_out = ctx @ out_w^T + out_b  (overwrites qh)
    gemm_tn<false, true><<<dim3(8, 512), blk, 0, stream>>>(
        cx, nullptr, 512, 512, out_w, out_b, qh, 512);
    // 9. h1_raw = [q | attn_out] @ p1_w^T + p1_b (overwrites cx)
    gemm_tn<true, true><<<dim3(8, 512), blk, 0, stream>>>(
        q, qh, 512, 1024, p1_w, p1_b, cx, 512);
    // 10. h1 = gelu(LN(h1_raw)) in-place
    ln_rows<true><<<32768, blk, 0, stream>>>(cx, ln1_g, ln1_b);
    // 11. h2_raw = h1 @ p2_w^T + p2_b  (overwrites q)
    gemm_tn<false, true><<<dim3(8, 512), blk, 0, stream>>>(
        cx, nullptr, 512, 512, p2_w, p2_b, q, 512);
    // 12. out = sigmoid((h1 + gelu(LN(h2_raw))) . head_w + head_b)
    final_head<<<32768, blk, 0, stream>>>(cx, q, ln2_g, ln2_b, head_w, head_b, out);
}

// Round 2
// 567.534 us; speedup vs baseline: 4.6327x; 4.6327x over previous
//
#include <hip/hip_runtime.h>
#include <math.h>

// L=32768 lines, M=8 neighbors, B=8192 blocks, LIN=BIN=768, H=512, NH=8, DH=64

typedef unsigned short u16;
typedef unsigned int u32;
using bf16x8 = __attribute__((ext_vector_type(8))) __bf16;
using f32x4  = __attribute__((ext_vector_type(4))) float;

__device__ __forceinline__ u16 f2bf(float f) {
    u32 u = __builtin_bit_cast(u32, f);
    u32 r = u + 0x7fffu + ((u >> 16) & 1u);
    return (u16)(r >> 16);
}
__device__ __forceinline__ float bf2f(u16 h) {
    return __builtin_bit_cast(float, (u32)h << 16);
}
__device__ __forceinline__ float gelu_exact(float x) {
    return 0.5f * x * (1.0f + erff(x * 0.70710678118654752440f));
}

// Block-wide reduction of two values across 256 threads (4 waves).
__device__ __forceinline__ void breduce2(float& s0, float& s1, float* sm) {
    #pragma unroll
    for (int off = 32; off > 0; off >>= 1) {
        s0 += __shfl_down(s0, off);
        s1 += __shfl_down(s1, off);
    }
    const int lane = threadIdx.x & 63, w = threadIdx.x >> 6;
    __syncthreads();
    if (lane == 0) { sm[w * 2] = s0; sm[w * 2 + 1] = s1; }
    __syncthreads();
    s0 = sm[0] + sm[2] + sm[4] + sm[6];
    s1 = sm[1] + sm[3] + sm[5] + sm[7];
}

// ---------------- fp32 -> bf16 conversion ----------------
__global__ __launch_bounds__(256) void cvt_bf16(
    const float* __restrict__ s, u16* __restrict__ d, int n)
{
    const int i = (blockIdx.x * 256 + threadIdx.x) * 4;
    if (i >= n) return;
    const float4 v = *reinterpret_cast<const float4*>(s + i);
    ushort4 o = make_ushort4(f2bf(v.x), f2bf(v.y), f2bf(v.z), f2bf(v.w));
    *reinterpret_cast<ushort4*>(d + i) = o;
}

// ---------------- bf16 MFMA GEMM: C[M,N] = A[M,K] @ W[N,K]^T (+bias) --------
// m97 structure: 128x128 tile, BK=32, 4 waves (2x2 of 64x64), global_load_lds
// staging into linear [128][32] bf16 LDS, mfma_f32_16x16x32_bf16.
// A may be split at column K1 (concat along K). Output fp32 or bf16.
template<bool HAS_A2, bool OUT_BF16>
__global__ __launch_bounds__(256) void gemm_bf16(
    const u16* __restrict__ A1, const u16* __restrict__ A2, int K1, int K,
    const u16* __restrict__ W, const float* __restrict__ bias,
    void* __restrict__ Cv, int N)
{
    __shared__ __bf16 As[128 * 32];
    __shared__ __bf16 Ws[128 * 32];
    const int tid = threadIdx.x;
    const int w = tid >> 6, lane = tid & 63;
    const int row0 = blockIdx.y * 128;
    const int col0 = blockIdx.x * 128;
    const int wr = (w >> 1) * 64, wc = (w & 1) * 64;   // wave origin in tile
    const int fr = lane & 15, fg = lane >> 4;

    // staging geometry: per wave 2 chunks of 1KB; LDS dest wave-uniform,
    // global src per-lane (lane's 16B = 8 contiguous bf16 along K).
    int srow[2], scol[2], soff[2];
    #pragma unroll
    for (int c = 0; c < 2; ++c) {
        const int bo = w * 2048 + c * 1024 + lane * 16;  // byte off in tile
        srow[c] = bo >> 6;          // tile row (64B per row)
        scol[c] = (bo & 63) >> 1;   // bf16 col within [0,32)
        soff[c] = (w * 2048 + c * 1024) >> 1;            // LDS elem offset
    }

    f32x4 acc[4][4] = {};

    for (int k0 = 0; k0 < K; k0 += 32) {
        #pragma unroll
        for (int c = 0; c < 2; ++c) {
            const u16* asrc;
            if (HAS_A2) {
                const bool first = (k0 < K1);
                const u16* base = first ? A1 : A2;
                const int ldk = first ? K1 : (K - K1);
                const int kk  = first ? k0 : (k0 - K1);
                asrc = base + (size_t)(row0 + srow[c]) * ldk + kk + scol[c];
            } else {
                asrc = A1 + (size_t)(row0 + srow[c]) * K + k0 + scol[c];
            }
            __builtin_amdgcn_global_load_lds(
                (const __attribute__((address_space(1))) u32*)asrc,
                (__attribute__((address_space(3))) u32*)(As + soff[c]), 16, 0, 0);
            const u16* wsrc = W + (size_t)(col0 + srow[c]) * K + k0 + scol[c];
            __builtin_amdgcn_global_load_lds(
                (const __attribute__((address_space(1))) u32*)wsrc,
                (__attribute__((address_space(3))) u32*)(Ws + soff[c]), 16, 0, 0);
        }
        __syncthreads();   // compiler drains vmcnt before s_barrier

        bf16x8 af[4], bfr[4];
        #pragma unroll
        for (int m = 0; m < 4; ++m) {
            af[m]  = *(const bf16x8*)(As + (wr + m * 16 + fr) * 32 + fg * 8);
            bfr[m] = *(const bf16x8*)(Ws + (wc + m * 16 + fr) * 32 + fg * 8);
        }
        #pragma unroll
        for (int m = 0; m < 4; ++m)
            #pragma unroll
            for (int n = 0; n < 4; ++n)
                acc[m][n] = __builtin_amdgcn_mfma_f32_16x16x32_bf16(
                    af[m], bfr[n], acc[m][n], 0, 0, 0);
        __syncthreads();
    }

    // epilogue: C/D layout col=lane&15, row=(lane>>4)*4+reg  [m89-verified]
    #pragma unroll
    for (int m = 0; m < 4; ++m) {
        #pragma unroll
        for (int n = 0; n < 4; ++n) {
            const int col = col0 + wc + n * 16 + fr;
            const float bv = bias ? bias[col] : 0.0f;
            #pragma unroll
            for (int r = 0; r < 4; ++r) {
                const int row = row0 + wr + m * 16 + fg * 4 + r;
                const float v = acc[m][n][r] + bv;
                if (OUT_BF16) ((u16*)Cv)[(size_t)row * N + col] = f2bf(v);
                else          ((float*)Cv)[(size_t)row * N + col] = v;
            }
        }
    }
}

// ---------------- Row LayerNorm (fp32 in, bf16 out), 512 cols, opt GELU -----
template<bool GELU>
__global__ __launch_bounds__(256) void ln_rows(
    const float* __restrict__ X, const float* __restrict__ g,
    const float* __restrict__ b, u16* __restrict__ Y)
{
    __shared__ float sm[8];
    const size_t base = (size_t)blockIdx.x * 512;
    const int t = threadIdx.x;
    const float x0 = X[base + t], x1 = X[base + t + 256];
    float s0 = x0 + x1, s1 = x0 * x0 + x1 * x1;
    breduce2(s0, s1, sm);
    const float mu = s0 * (1.0f / 512.0f);
    const float var = s1 * (1.0f / 512.0f) - mu * mu;
    const float rs = rsqrtf(var + 1e-5f);
    float y0 = (x0 - mu) * rs * g[t] + b[t];
    float y1 = (x1 - mu) * rs * g[t + 256] + b[t + 256];
    if (GELU) { y0 = gelu_exact(y0); y1 = gelu_exact(y1); }
    Y[base + t] = f2bf(y0); Y[base + t + 256] = f2bf(y1);
}

// ---------------- Attention: one block per line, one wave per head ----------
__global__ __launch_bounds__(512) void attn_kernel(
    const u16* __restrict__ qh, const u16* __restrict__ kvb,
    const int* __restrict__ kidx, const int* __restrict__ ncnt,
    u16* __restrict__ ctx)
{
    const int l = blockIdx.x;
    const int head = threadIdx.x >> 6;
    const int lane = threadIdx.x & 63;
    const int cnt = ncnt[l];
    const float qv = bf2f(qh[(size_t)l * 512 + head * 64 + lane]);
    int idx[8];
    #pragma unroll
    for (int m = 0; m < 8; ++m) idx[m] = kidx[l * 8 + m];
    float sc[8];
    #pragma unroll
    for (int m = 0; m < 8; ++m) {
        float p = qv * bf2f(kvb[(size_t)idx[m] * 1024 + head * 64 + lane]);
        #pragma unroll
        for (int off = 32; off > 0; off >>= 1) p += __shfl_xor(p, off);
        sc[m] = (m < cnt) ? p * 0.125f : -3.402823466e38f;
    }
    float mx = sc[0];
    #pragma unroll
    for (int m = 1; m < 8; ++m) mx = fmaxf(mx, sc[m]);
    float wgt[8], s = 0.0f;
    #pragma unroll
    for (int m = 0; m < 8; ++m) { wgt[m] = expf(sc[m] - mx); s += wgt[m]; }
    float o = 0.0f;
    #pragma unroll
    for (int m = 0; m < 8; ++m)
        o += wgt[m] * bf2f(kvb[(size_t)idx[m] * 1024 + 512 + head * 64 + lane]);
    ctx[(size_t)l * 512 + head * 64 + lane] = f2bf(o / s);
}

// ---------------- Final: h2 = h1 + gelu(LN(h2_raw)); sigmoid(head) ----------
__global__ __launch_bounds__(256) void final_head(
    const u16* __restrict__ h1, const float* __restrict__ h2raw,
    const float* __restrict__ g, const float* __restrict__ b,
    const float* __restrict__ hw, const float* __restrict__ hb,
    float* __restrict__ out)
{
    __shared__ float sm[8];
    const size_t base = (size_t)blockIdx.x * 512;
    const int t = threadIdx.x;
    const float x0 = h2raw[base + t], x1 = h2raw[base + t + 256];
    float s0 = x0 + x1, s1 = x0 * x0 + x1 * x1;
    breduce2(s0, s1, sm);
    const float mu = s0 * (1.0f / 512.0f);
    const float var = s1 * (1.0f / 512.0f) - mu * mu;
    const float rs = rsqrtf(var + 1e-5f);
    const float y0 = bf2f(h1[base + t])       + gelu_exact((x0 - mu) * rs * g[t]       + b[t]);
    const float y1 = bf2f(h1[base + t + 256]) + gelu_exact((x1 - mu) * rs * g[t + 256] + b[t + 256]);
    float d0 = y0 * hw[t] + y1 * hw[t + 256], d1 = 0.0f;
    breduce2(d0, d1, sm);
    if (t == 0) out[blockIdx.x] = 1.0f / (1.0f + expf(-(d0 + hb[0])));
}

extern "C" void kernel_launch(void* const* d_in, const int* in_sizes, int n_in,
                              void* d_out, int out_size, void* d_ws, size_t ws_size,
                              hipStream_t stream)
{
    const float* lines  = (const float*)d_in[0];   // [32768,768]
    const float* blocks = (const float*)d_in[1];   // [8192,768]
    const float* Wq     = (const float*)d_in[2];   // [512,768]
    const float* Wkv    = (const float*)d_in[3];   // [512,768]
    const float* qn_g   = (const float*)d_in[4];
    const float* qn_b   = (const float*)d_in[5];
    const float* kvn_g  = (const float*)d_in[6];
    const float* kvn_b  = (const float*)d_in[7];
    const float* in_w   = (const float*)d_in[8];   // [1536,512]
    const float* in_b   = (const float*)d_in[9];   // [1536]
    const float* out_w  = (const float*)d_in[10];  // [512,512]
    const float* out_b  = (const float*)d_in[11];
    const float* p1_w   = (const float*)d_in[12];  // [512,1024]
    const float* p1_b   = (const float*)d_in[13];
    const float* ln1_g  = (const float*)d_in[14];
    const float* ln1_b  = (const float*)d_in[15];
    const float* p2_w   = (const float*)d_in[16];  // [512,512]
    const float* p2_b   = (const float*)d_in[17];
    const float* ln2_g  = (const float*)d_in[18];
    const float* ln2_b  = (const float*)d_in[19];
    const float* head_w = (const float*)d_in[20];  // [1,512]
    const float* head_b = (const float*)d_in[21];  // [1]
    const int*   kidx   = (const int*)d_in[22];    // [32768,8]
    const int*   ncnt   = (const int*)d_in[23];    // [32768]
    float* out = (float*)d_out;                    // [32768]

    // workspace layout (byte offsets; aliasing justified by liveness):
    //   [0,64M)    Sf   fp32 scratch (q_raw / h1_raw / h2_raw; bkv_raw in [0,16M))
    //   [16M,28M)  Bb   bf16 blocks (dead before Sf's first full write)
    //   [64M,96M)  qb   bf16 q
    //   [96M,144M) Lb   bf16 lines (dead before qhb/ctxb written)
    //   [96M,128M) qhb  bf16 qh -> attn_out
    //   [128M,160M)ctxb bf16 ctx -> h1
    //   [160M,176M)kvbb bf16 [8192,1024] k|v
    //   [176M,184M)bkvb bf16 LN'd block kv basis
    //   [184M,~189M) bf16 weights
    char* wsb = (char*)d_ws;
    float* Sf   = (float*)(wsb);
    float* bkvf = Sf;
    u16* Bb     = (u16*)(wsb + (16ull << 20));
    u16* qb     = (u16*)(wsb + (64ull << 20));
    u16* qhb    = (u16*)(wsb + (96ull << 20));
    u16* Lb     = (u16*)(wsb + (96ull << 20));
    u16* ctxb   = (u16*)(wsb + (128ull << 20));
    u16* kvbb   = (u16*)(wsb + (160ull << 20));
    u16* bkvb   = (u16*)(wsb + (176ull << 20));
    u16* Wqb    = (u16*)(wsb + (184ull << 20));
    u16* Wkvb   = Wqb + 512 * 768;
    u16* inwb   = Wkvb + 512 * 768;
    u16* outwb  = inwb + 1536 * 512;
    u16* p1wb   = outwb + 512 * 512;
    u16* p2wb   = p1wb + 512 * 1024;

    auto cvt = [&](const float* s, u16* d, int n) {
        cvt_bf16<<<(n / 4 + 255) / 256, 256, 0, stream>>>(s, d, n);
    };
    cvt(lines, Lb, 32768 * 768);
    cvt(blocks, Bb, 8192 * 768);
    cvt(Wq, Wqb, 512 * 768);
    cvt(Wkv, Wkvb, 512 * 768);
    cvt(in_w, inwb, 1536 * 512);
    cvt(out_w, outwb, 512 * 512);
    cvt(p1_w, p1wb, 512 * 1024);
    cvt(p2_w, p2wb, 512 * 512);

    // 1. bkv_raw = blocks @ Wkv^T                 [8192,512] fp32
    gemm_bf16<false, false><<<dim3(4, 64), 256, 0, stream>>>(
        Bb, nullptr, 768, 768, Wkvb, nullptr, bkvf, 512);
    // 2. bkvb = LN(bkv_raw)                       bf16
    ln_rows<false><<<8192, 256, 0, stream>>>(bkvf, kvn_g, kvn_b, bkvb);
    // 3. kvbb = bkvb @ [wk;wv]^T + [bk;bv]        [8192,1024] bf16
    gemm_bf16<false, true><<<dim3(8, 64), 256, 0, stream>>>(
        bkvb, nullptr, 512, 512, inwb + 512 * 512, in_b + 512, kvbb, 1024);
    // 4. q_raw = lines @ Wq^T                     [32768,512] fp32
    gemm_bf16<false, false><<<dim3(4, 256), 256, 0, stream>>>(
        Lb, nullptr, 768, 768, Wqb, nullptr, Sf, 512);
    // 5. qb = LN(q_raw)                           bf16
    ln_rows<false><<<32768, 256, 0, stream>>>(Sf, qn_g, qn_b, qb);
    // 6. qhb = qb @ wq_i^T + bq_i                 [32768,512] bf16
    gemm_bf16<false, true><<<dim3(4, 256), 256, 0, stream>>>(
        qb, nullptr, 512, 512, inwb, in_b, qhb, 512);
    // 7. ctxb (attention)                         bf16
    attn_kernel<<<32768, 512, 0, stream>>>(qhb, kvbb, kidx, ncnt, ctxb);
    // 8. attn_out = ctxb @ out_w^T + out_b  (into qhb, qh now dead)
    gemm_bf16<false, true><<<dim3(4, 256), 256, 0, stream>>>(
        ctxb, nullptr, 512, 512, outwb, out_b, qhb, 512);
    // 9. h1_raw = [qb | attn_out] @ p1_w^T + p1_b [32768,512] fp32 into Sf
    gemm_bf16<true, false><<<dim3(4, 256), 256, 0, stream>>>(
        qb, qhb, 512, 1024, p1wb, p1_b, Sf, 512);
    // 10. h1 = gelu(LN(h1_raw))  bf16 into ctxb (ctx dead)
    ln_rows<true><<<32768, 256, 0, stream>>>(Sf, ln1_g, ln1_b, ctxb);
    // 11. h2_raw = h1 @ p2_w^T + p2_b             [32768,512] fp32 into Sf
    gemm_bf16<false, false><<<dim3(4, 256), 256, 0, stream>>>(
        ctxb, nullptr, 512, 512, p2wb, p2_b, Sf, 512);
    // 12. out = sigmoid((h1 + gelu(LN(h2_raw))) . head_w + head_b)
    final_head<<<32768, 256, 0, stream>>>(ctxb, Sf, ln2_g, ln2_b, head_w, head_b, out);
}

// Round 3
// 516.634 us; speedup vs baseline: 5.0891x; 1.0985x over previous
//
#include <hip/hip_runtime.h>
#include <math.h>

// L=32768 lines, M=8 neighbors, B=8192 blocks, LIN=BIN=768, H=512, NH=8, DH=64

typedef unsigned short u16;
typedef unsigned int u32;
using bf16x8 = __attribute__((ext_vector_type(8))) __bf16;
using u16x8  = __attribute__((ext_vector_type(8))) u16;
using f32x4  = __attribute__((ext_vector_type(4))) float;

__device__ __forceinline__ u16 f2bf(float f) {
    u32 u = __builtin_bit_cast(u32, f);
    u32 r = u + 0x7fffu + ((u >> 16) & 1u);
    return (u16)(r >> 16);
}
__device__ __forceinline__ float bf2f(u16 h) {
    return __builtin_bit_cast(float, (u32)h << 16);
}
__device__ __forceinline__ float gelu_exact(float x) {
    return 0.5f * x * (1.0f + erff(x * 0.70710678118654752440f));
}

// Block-wide reduction of two values across 256 threads (4 waves).
__device__ __forceinline__ void breduce2(float& s0, float& s1, float* sm) {
    #pragma unroll
    for (int off = 32; off > 0; off >>= 1) {
        s0 += __shfl_down(s0, off);
        s1 += __shfl_down(s1, off);
    }
    const int lane = threadIdx.x & 63, w = threadIdx.x >> 6;
    __syncthreads();
    if (lane == 0) { sm[w * 2] = s0; sm[w * 2 + 1] = s1; }
    __syncthreads();
    s0 = sm[0] + sm[2] + sm[4] + sm[6];
    s1 = sm[1] + sm[3] + sm[5] + sm[7];
}

// ---------------- fp32 -> bf16 conversion (large arrays) ----------------
__global__ __launch_bounds__(256) void cvt_bf16(
    const float* __restrict__ s, u16* __restrict__ d, int n)
{
    const int i = (blockIdx.x * 256 + threadIdx.x) * 4;
    if (i >= n) return;
    const float4 v = *reinterpret_cast<const float4*>(s + i);
    ushort4 o = make_ushort4(f2bf(v.x), f2bf(v.y), f2bf(v.z), f2bf(v.w));
    *reinterpret_cast<ushort4*>(d + i) = o;
}

// ---------------- fused multi-array conversion (weights) ----------------
struct CvtJobs {
    const float* s[6];
    u16* d[6];
    int cum[7];   // cumulative quad counts
};
__global__ __launch_bounds__(256) void cvt_multi(CvtJobs j)
{
    const int g = blockIdx.x * 256 + threadIdx.x;   // quad index
    if (g >= j.cum[6]) return;
    int seg = 0;
    #pragma unroll
    for (int k = 1; k < 6; ++k) seg += (g >= j.cum[k]);
    const int q = g - j.cum[seg];
    const float4 v = *reinterpret_cast<const float4*>(j.s[seg] + q * 4);
    ushort4 o = make_ushort4(f2bf(v.x), f2bf(v.y), f2bf(v.z), f2bf(v.w));
    *reinterpret_cast<ushort4*>(j.d[seg] + q * 4) = o;
}

// ---------------- bf16 MFMA GEMM: C[M,N] = A[M,K] @ W[N,K]^T (+bias) --------
// m97 structure: 128x128 tile, BK=32, 4 waves, global_load_lds width-16
// staging into linear [128][32] bf16 LDS, mfma_f32_16x16x32_bf16.
template<bool HAS_A2, bool OUT_BF16>
__global__ __launch_bounds__(256) void gemm_bf16(
    const u16* __restrict__ A1, const u16* __restrict__ A2, int K1, int K,
    const u16* __restrict__ W, const float* __restrict__ bias,
    void* __restrict__ Cv, int N)
{
    __shared__ __bf16 As[128 * 32];
    __shared__ __bf16 Ws[128 * 32];
    const int tid = threadIdx.x;
    const int w = tid >> 6, lane = tid & 63;
    const int row0 = blockIdx.y * 128;
    const int col0 = blockIdx.x * 128;
    const int wr = (w >> 1) * 64, wc = (w & 1) * 64;
    const int fr = lane & 15, fg = lane >> 4;

    int srow[2], scol[2], soff[2];
    #pragma unroll
    for (int c = 0; c < 2; ++c) {
        const int bo = w * 2048 + c * 1024 + lane * 16;
        srow[c] = bo >> 6;
        scol[c] = (bo & 63) >> 1;
        soff[c] = (w * 2048 + c * 1024) >> 1;
    }

    f32x4 acc[4][4] = {};

    for (int k0 = 0; k0 < K; k0 += 32) {
        #pragma unroll
        for (int c = 0; c < 2; ++c) {
            const u16* asrc;
            if (HAS_A2) {
                const bool first = (k0 < K1);
                const u16* base = first ? A1 : A2;
                const int ldk = first ? K1 : (K - K1);
                const int kk  = first ? k0 : (k0 - K1);
                asrc = base + (size_t)(row0 + srow[c]) * ldk + kk + scol[c];
            } else {
                asrc = A1 + (size_t)(row0 + srow[c]) * K + k0 + scol[c];
            }
            __builtin_amdgcn_global_load_lds(
                (const __attribute__((address_space(1))) u32*)asrc,
                (__attribute__((address_space(3))) u32*)(As + soff[c]), 16, 0, 0);
            const u16* wsrc = W + (size_t)(col0 + srow[c]) * K + k0 + scol[c];
            __builtin_amdgcn_global_load_lds(
                (const __attribute__((address_space(1))) u32*)wsrc,
                (__attribute__((address_space(3))) u32*)(Ws + soff[c]), 16, 0, 0);
        }
        __syncthreads();

        bf16x8 af[4], bfr[4];
        #pragma unroll
        for (int m = 0; m < 4; ++m) {
            af[m]  = *(const bf16x8*)(As + (wr + m * 16 + fr) * 32 + fg * 8);
            bfr[m] = *(const bf16x8*)(Ws + (wc + m * 16 + fr) * 32 + fg * 8);
        }
        #pragma unroll
        for (int m = 0; m < 4; ++m)
            #pragma unroll
            for (int n = 0; n < 4; ++n)
                acc[m][n] = __builtin_amdgcn_mfma_f32_16x16x32_bf16(
                    af[m], bfr[n], acc[m][n], 0, 0, 0);
        __syncthreads();
    }

    #pragma unroll
    for (int m = 0; m < 4; ++m) {
        #pragma unroll
        for (int n = 0; n < 4; ++n) {
            const int col = col0 + wc + n * 16 + fr;
            const float bv = bias ? bias[col] : 0.0f;
            #pragma unroll
            for (int r = 0; r < 4; ++r) {
                const int row = row0 + wr + m * 16 + fg * 4 + r;
                const float v = acc[m][n][r] + bv;
                if (OUT_BF16) ((u16*)Cv)[(size_t)row * N + col] = f2bf(v);
                else          ((float*)Cv)[(size_t)row * N + col] = v;
            }
        }
    }
}

// ---------------- Row LayerNorm (fp32 in, bf16 out), 512 cols, opt GELU -----
template<bool GELU>
__global__ __launch_bounds__(256) void ln_rows(
    const float* __restrict__ X, const float* __restrict__ g,
    const float* __restrict__ b, u16* __restrict__ Y)
{
    __shared__ float sm[8];
    const size_t base = (size_t)blockIdx.x * 512;
    const int t = threadIdx.x;
    const float x0 = X[base + t], x1 = X[base + t + 256];
    float s0 = x0 + x1, s1 = x0 * x0 + x1 * x1;
    breduce2(s0, s1, sm);
    const float mu = s0 * (1.0f / 512.0f);
    const float var = s1 * (1.0f / 512.0f) - mu * mu;
    const float rs = rsqrtf(var + 1e-5f);
    float y0 = (x0 - mu) * rs * g[t] + b[t];
    float y1 = (x1 - mu) * rs * g[t + 256] + b[t + 256];
    if (GELU) { y0 = gelu_exact(y0); y1 = gelu_exact(y1); }
    Y[base + t] = f2bf(y0); Y[base + t + 256] = f2bf(y1);
}

// ---------------- Attention: wave per (line, head); lane = dgroup*8 + m -----
// QK reduce: 3 shfl (masks 8/16/32); softmax over m: 6 shfl (1/2/4);
// PV: value-halving butterfly, 7 shfl; each lane ends with one output elem.
__global__ __launch_bounds__(512) void attn_kernel(
    const u16* __restrict__ qh, const u16* __restrict__ kvb,
    const int* __restrict__ kidx, const int* __restrict__ ncnt,
    u16* __restrict__ ctx)
{
    const int l = blockIdx.x;
    const int head = threadIdx.x >> 6;
    const int lane = threadIdx.x & 63;
    const int mi = lane & 7, dg = lane >> 3;
    const int cnt = ncnt[l];
    const int idx = kidx[l * 8 + mi];

    // QK^T partial over this lane's 8 dims
    const u16x8 qv = *(const u16x8*)(qh + (size_t)l * 512 + head * 64 + dg * 8);
    const u16x8 kv = *(const u16x8*)(kvb + (size_t)idx * 1024 + head * 64 + dg * 8);
    float p = 0.0f;
    #pragma unroll
    for (int jj = 0; jj < 8; ++jj) p = fmaf(bf2f(qv[jj]), bf2f(kv[jj]), p);
    p += __shfl_xor(p, 8); p += __shfl_xor(p, 16); p += __shfl_xor(p, 32);

    float s = (mi < cnt) ? p * 0.125f : -3.402823466e38f;
    float mx = s;
    mx = fmaxf(mx, __shfl_xor(mx, 1));
    mx = fmaxf(mx, __shfl_xor(mx, 2));
    mx = fmaxf(mx, __shfl_xor(mx, 4));
    const float e = __expf(s - mx);
    float den = e;
    den += __shfl_xor(den, 1); den += __shfl_xor(den, 2); den += __shfl_xor(den, 4);
    const float wgt = e / den;

    // PV: c[j] = w * v[idx[mi]][dg*8+j], then halving-butterfly sum over mi
    const u16x8 vv = *(const u16x8*)(kvb + (size_t)idx * 1024 + 512 + head * 64 + dg * 8);
    float c[8];
    #pragma unroll
    for (int jj = 0; jj < 8; ++jj) c[jj] = wgt * bf2f(vv[jj]);

    const bool b0 = (mi & 1), b1 = (mi & 2), b2 = (mi & 4);
    #pragma unroll
    for (int jj = 0; jj < 4; ++jj) {
        const float snd = b0 ? c[jj] : c[jj + 4];
        const float rec = __shfl_xor(snd, 1);
        c[jj] = (b0 ? c[jj + 4] : c[jj]) + rec;
    }
    #pragma unroll
    for (int jj = 0; jj < 2; ++jj) {
        const float snd = b1 ? c[jj] : c[jj + 2];
        const float rec = __shfl_xor(snd, 2);
        c[jj] = (b1 ? c[jj + 2] : c[jj]) + rec;
    }
    {
        const float snd = b2 ? c[0] : c[1];
        const float rec = __shfl_xor(snd, 4);
        c[0] = (b2 ? c[1] : c[0]) + rec;
    }
    // lane (dg, mi=b2b1b0) owns d = dg*8 + 4*b0 + 2*b1 + b2 (bit-reversed mi)
    const int doff = (b0 ? 4 : 0) + (b1 ? 2 : 0) + (b2 ? 1 : 0);
    ctx[(size_t)l * 512 + head * 64 + dg * 8 + doff] = f2bf(c[0]);
}

// ---------------- Final: h2 = h1 + gelu(LN(h2_raw)); sigmoid(head) ----------
__global__ __launch_bounds__(256) void final_head(
    const u16* __restrict__ h1, const float* __restrict__ h2raw,
    const float* __restrict__ g, const float* __restrict__ b,
    const float* __restrict__ hw, const float* __restrict__ hb,
    float* __restrict__ out)
{
    __shared__ float sm[8];
    const size_t base = (size_t)blockIdx.x * 512;
    const int t = threadIdx.x;
    const float x0 = h2raw[base + t], x1 = h2raw[base + t + 256];
    float s0 = x0 + x1, s1 = x0 * x0 + x1 * x1;
    breduce2(s0, s1, sm);
    const float mu = s0 * (1.0f / 512.0f);
    const float var = s1 * (1.0f / 512.0f) - mu * mu;
    const float rs = rsqrtf(var + 1e-5f);
    const float y0 = bf2f(h1[base + t])       + gelu_exact((x0 - mu) * rs * g[t]       + b[t]);
    const float y1 = bf2f(h1[base + t + 256]) + gelu_exact((x1 - mu) * rs * g[t + 256] + b[t + 256]);
    float d0 = y0 * hw[t] + y1 * hw[t + 256], d1 = 0.0f;
    breduce2(d0, d1, sm);
    if (t == 0) out[blockIdx.x] = 1.0f / (1.0f + expf(-(d0 + hb[0])));
}

extern "C" void kernel_launch(void* const* d_in, const int* in_sizes, int n_in,
                              void* d_out, int out_size, void* d_ws, size_t ws_size,
                              hipStream_t stream)
{
    const float* lines  = (const float*)d_in[0];   // [32768,768]
    const float* blocks = (const float*)d_in[1];   // [8192,768]
    const float* Wq     = (const float*)d_in[2];   // [512,768]
    const float* Wkv    = (const float*)d_in[3];   // [512,768]
    const float* qn_g   = (const float*)d_in[4];
    const float* qn_b   = (const float*)d_in[5];
    const float* kvn_g  = (const float*)d_in[6];
    const float* kvn_b  = (const float*)d_in[7];
    const float* in_w   = (const float*)d_in[8];   // [1536,512]
    const float* in_b   = (const float*)d_in[9];   // [1536]
    const float* out_w  = (const float*)d_in[10];  // [512,512]
    const float* out_b  = (const float*)d_in[11];
    const float* p1_w   = (const float*)d_in[12];  // [512,1024]
    const float* p1_b   = (const float*)d_in[13];
    const float* ln1_g  = (const float*)d_in[14];
    const float* ln1_b  = (const float*)d_in[15];
    const float* p2_w   = (const float*)d_in[16];  // [512,512]
    const float* p2_b   = (const float*)d_in[17];
    const float* ln2_g  = (const float*)d_in[18];
    const float* ln2_b  = (const float*)d_in[19];
    const float* head_w = (const float*)d_in[20];  // [1,512]
    const float* head_b = (const float*)d_in[21];  // [1]
    const int*   kidx   = (const int*)d_in[22];    // [32768,8]
    const int*   ncnt   = (const int*)d_in[23];    // [32768]
    float* out = (float*)d_out;                    // [32768]

    char* wsb = (char*)d_ws;
    float* Sf   = (float*)(wsb);                    // fp32 scratch [0,64M)
    float* bkvf = Sf;
    u16* Bb     = (u16*)(wsb + (16ull << 20));
    u16* qb     = (u16*)(wsb + (64ull << 20));
    u16* qhb    = (u16*)(wsb + (96ull << 20));
    u16* Lb     = (u16*)(wsb + (96ull << 20));
    u16* ctxb   = (u16*)(wsb + (128ull << 20));
    u16* kvbb   = (u16*)(wsb + (160ull << 20));
    u16* bkvb   = (u16*)(wsb + (176ull << 20));
    u16* Wqb    = (u16*)(wsb + (184ull << 20));
    u16* Wkvb   = Wqb + 512 * 768;
    u16* inwb   = Wkvb + 512 * 768;
    u16* outwb  = inwb + 1536 * 512;
    u16* p1wb   = outwb + 512 * 512;
    u16* p2wb   = p1wb + 512 * 1024;

    // big activations: separate launches
    cvt_bf16<<<(32768 * 768 / 4 + 255) / 256, 256, 0, stream>>>(lines, Lb, 32768 * 768);
    cvt_bf16<<<(8192 * 768 / 4 + 255) / 256, 256, 0, stream>>>(blocks, Bb, 8192 * 768);
    // weights: one fused launch
    {
        CvtJobs j;
        const float* ss[6] = { Wq, Wkv, in_w, out_w, p1_w, p2_w };
        u16* dd[6] = { Wqb, Wkvb, inwb, outwb, p1wb, p2wb };
        const int nn[6] = { 512 * 768, 512 * 768, 1536 * 512, 512 * 512, 512 * 1024, 512 * 512 };
        int c = 0;
        for (int k = 0; k < 6; ++k) { j.s[k] = ss[k]; j.d[k] = dd[k]; j.cum[k] = c; c += nn[k] / 4; }
        j.cum[6] = c;
        cvt_multi<<<(c + 255) / 256, 256, 0, stream>>>(j);
    }

    // 1. bkv_raw = blocks @ Wkv^T                 [8192,512] fp32
    gemm_bf16<false, false><<<dim3(4, 64), 256, 0, stream>>>(
        Bb, nullptr, 768, 768, Wkvb, nullptr, bkvf, 512);
    // 2. bkvb = LN(bkv_raw)                       bf16
    ln_rows<false><<<8192, 256, 0, stream>>>(bkvf, kvn_g, kvn_b, bkvb);
    // 3. kvbb = bkvb @ [wk;wv]^T + [bk;bv]        [8192,1024] bf16
    gemm_bf16<false, true><<<dim3(8, 64), 256, 0, stream>>>(
        bkvb, nullptr, 512, 512, inwb + 512 * 512, in_b + 512, kvbb, 1024);
    // 4. q_raw = lines @ Wq^T                     [32768,512] fp32
    gemm_bf16<false, false><<<dim3(4, 256), 256, 0, stream>>>(
        Lb, nullptr, 768, 768, Wqb, nullptr, Sf, 512);
    // 5. qb = LN(q_raw)                           bf16
    ln_rows<false><<<32768, 256, 0, stream>>>(Sf, qn_g, qn_b, qb);
    // 6. qhb = qb @ wq_i^T + bq_i                 [32768,512] bf16
    gemm_bf16<false, true><<<dim3(4, 256), 256, 0, stream>>>(
        qb, nullptr, 512, 512, inwb, in_b, qhb, 512);
    // 7. ctxb (attention)
    attn_kernel<<<32768, 512, 0, stream>>>(qhb, kvbb, kidx, ncnt, ctxb);
    // 8. attn_out = ctxb @ out_w^T + out_b  (into qhb)
    gemm_bf16<false, true><<<dim3(4, 256), 256, 0, stream>>>(
        ctxb, nullptr, 512, 512, outwb, out_b, qhb, 512);
    // 9. h1_raw = [qb | attn_out] @ p1_w^T + p1_b [32768,512] fp32
    gemm_bf16<true, false><<<dim3(4, 256), 256, 0, stream>>>(
        qb, qhb, 512, 1024, p1wb, p1_b, Sf, 512);
    // 10. h1 = gelu(LN(h1_raw))  bf16 into ctxb
    ln_rows<true><<<32768, 256, 0, stream>>>(Sf, ln1_g, ln1_b, ctxb);
    // 11. h2_raw = h1 @ p2_w^T + p2_b             [32768,512] fp32
    gemm_bf16<false, false><<<dim3(4, 256), 256, 0, stream>>>(
        ctxb, nullptr, 512, 512, p2wb, p2_b, Sf, 512);
    // 12. out = sigmoid((h1 + gelu(LN(h2_raw))) . head_w + head_b)
    final_head<<<32768, 256, 0, stream>>>(ctxb, Sf, ln2_g, ln2_b, head_w, head_b, out);
}